// Round 1
// baseline (145.152 us; speedup 1.0000x reference)
//
#include <hip/hip_runtime.h>

// Problem constants (fixed by the reference):
//   B=2048, T=200, F=64, H=128, L=1
// Key simplification: L=1 and h=c=0 initially, so:
//   - W_hh einsum is identically zero (h=0)  -> W_hh, and the f-gate, are dead
//   - only the timestep idx=max(x_len-1,0) per batch row is ever read out
// True work: per row b, gates i/g/o = W_ih[rows]·x[b,idx,:] + b_ih + b_hh,
//   c = sigmoid(i)*tanh(g), h = sigmoid(o)*tanh(c).
// Output layout: [hs (B*H)] ++ [cs (B*H)], fp32.

namespace {
constexpr int Bc = 2048;
constexpr int Tc = 200;
constexpr int Fc = 64;
constexpr int Hc = 128;
constexpr int TF = Tc * Fc;            // 12800
constexpr int ROWS_PER_BLOCK = 8;      // batch rows per block
}

__global__ __launch_bounds__(256, 1)
void lstm_last_step_kernel(const float* __restrict__ x,     // [B,T,F]
                           const int*   __restrict__ xlen,  // [B]
                           const float* __restrict__ W,     // W_ih [4H, F]
                           const float* __restrict__ b_ih,  // [4H]
                           const float* __restrict__ b_hh,  // [4H]
                           float*       __restrict__ out)   // [2*B*H]
{
  const int t = threadIdx.x;
  const int j = t & (Hc - 1);   // gate column 0..127
  const int r = t >> 7;         // 0/1: which row of the pair this thread computes
  const int b0 = blockIdx.x * ROWS_PER_BLOCK;

  // ---- Load this thread's 3 needed W_ih rows (i, g, o) into registers ----
  // Rows: i -> j, g -> 2H+j, o -> 3H+j  (f-gate row H+j is dead: c_prev==0)
  float4 wi[16], wg[16], wo[16];
  const float4* W4 = reinterpret_cast<const float4*>(W);
  #pragma unroll
  for (int q = 0; q < 16; ++q) {
    wi[q] = W4[(0 * Hc + j) * 16 + q];
    wg[q] = W4[(2 * Hc + j) * 16 + q];
    wo[q] = W4[(3 * Hc + j) * 16 + q];
  }
  const float bi = b_ih[0 * Hc + j] + b_hh[0 * Hc + j];
  const float bg = b_ih[2 * Hc + j] + b_hh[2 * Hc + j];
  const float bo = b_ih[3 * Hc + j] + b_hh[3 * Hc + j];

  // ---- Stage the 8 gathered x rows for this block into LDS ----
  __shared__ float xs[ROWS_PER_BLOCK][Fc];   // 2 KB
  #pragma unroll
  for (int k = 0; k < 2; ++k) {
    const int lin = t + 256 * k;     // 0..511
    const int rr  = lin >> 6;        // local row 0..7
    const int f   = lin & 63;
    const int b   = b0 + rr;
    const int len = xlen[b];
    const int idx = (len == 0) ? 0 : (len - 1);
    xs[rr][f] = x[b * TF + idx * Fc + f];
  }
  __syncthreads();

  // ---- Compute 2 rows at a time (r selects which), 4 iterations = 8 rows ----
  #pragma unroll
  for (int p = 0; p < 4; ++p) {
    const int rowlocal = p * 2 + r;          // wave-uniform
    const int b = b0 + rowlocal;
    const float4* xv = reinterpret_cast<const float4*>(xs[rowlocal]);

    float ai = bi, ag = bg, ao = bo;
    #pragma unroll
    for (int q = 0; q < 16; ++q) {
      const float4 xq = xv[q];               // wave-uniform address -> LDS broadcast
      ai = fmaf(wi[q].x, xq.x, ai);
      ai = fmaf(wi[q].y, xq.y, ai);
      ai = fmaf(wi[q].z, xq.z, ai);
      ai = fmaf(wi[q].w, xq.w, ai);
      ag = fmaf(wg[q].x, xq.x, ag);
      ag = fmaf(wg[q].y, xq.y, ag);
      ag = fmaf(wg[q].z, xq.z, ag);
      ag = fmaf(wg[q].w, xq.w, ag);
      ao = fmaf(wo[q].x, xq.x, ao);
      ao = fmaf(wo[q].y, xq.y, ao);
      ao = fmaf(wo[q].z, xq.z, ao);
      ao = fmaf(wo[q].w, xq.w, ao);
    }

    const float si = 1.0f / (1.0f + expf(-ai));
    const float so = 1.0f / (1.0f + expf(-ao));
    const float tg = tanhf(ag);
    const float c  = si * tg;
    const float h  = so * tanhf(c);

    out[b * Hc + j]           = h;   // hs block: [0, B*H)
    out[Bc * Hc + b * Hc + j] = c;   // cs block: [B*H, 2*B*H)
  }
}

extern "C" void kernel_launch(void* const* d_in, const int* in_sizes, int n_in,
                              void* d_out, int out_size, void* d_ws, size_t ws_size,
                              hipStream_t stream) {
  // setup_inputs order: encode_features, x_len, W_ih, W_hh, b_ih, b_hh
  const float* x     = (const float*)d_in[0];
  const int*   xlen  = (const int*)  d_in[1];
  const float* W_ih  = (const float*)d_in[2];
  // d_in[3] = W_hh : provably unused (h_prev == 0)
  const float* b_ih  = (const float*)d_in[4];
  const float* b_hh  = (const float*)d_in[5];
  float*       out   = (float*)d_out;

  lstm_last_step_kernel<<<Bc / ROWS_PER_BLOCK, 256, 0, stream>>>(
      x, xlen, W_ih, b_ih, b_hh, out);
}